// Round 1
// baseline (825.874 us; speedup 1.0000x reference)
//
#include <hip/hip_runtime.h>
#include <math.h>

// Problem constants (match reference)
#define DEPTH   5
#define MAXF    4
#define HIDDEN  128
#define CODE    400
#define NFREQ   9
#define BATCH   8
#define NPTS_B  32768
#define NPTS    (BATCH * NPTS_B)   // 262144

#define PTS_PER_BLOCK 64
#define BLOCK         256

// ---------------------------------------------------------------------------
// Kernel 1: code term  cterm[i][b][h] = sum_c a[b][c]*Wcode[i][h][c]
//                                       + bcode[i][h] + bfwd[i][h]
// grid = DEPTH*BATCH blocks, 128 threads
// ---------------------------------------------------------------------------
__global__ void sinr_cterm(const float* __restrict__ a,
                           const float* __restrict__ Wcode,
                           const float* __restrict__ bcode,
                           const float* __restrict__ bfwd,
                           float* __restrict__ cterm) {
    int i = blockIdx.x / BATCH;   // layer
    int b = blockIdx.x % BATCH;   // batch
    int h = threadIdx.x;          // hidden idx
    const float* ar = a + b * CODE;
    const float* wr = Wcode + (i * HIDDEN + h) * CODE;
    float acc = bcode[i * HIDDEN + h] + bfwd[i * HIDDEN + h];
    for (int c = 0; c < CODE; c += 4) {
        float4 av = *(const float4*)(ar + c);
        float4 wv = *(const float4*)(wr + c);
        acc = fmaf(av.x, wv.x, acc);
        acc = fmaf(av.y, wv.y, acc);
        acc = fmaf(av.z, wv.z, acc);
        acc = fmaf(av.w, wv.w, acc);
    }
    cterm[(i * BATCH + b) * HIDDEN + h] = acc;
}

// ---------------------------------------------------------------------------
// Kernel 2: main fused pipeline.
// Block: 256 threads, 64 points. z kept in LDS [64][132] fp32.
// Each thread owns a 4-point x 8-hidden accumulator tile.
// Wfwd staged into LDS in 16-wide K chunks, transposed to [h][g] so the
// g-dimension vectorizes as float4.
// ---------------------------------------------------------------------------
__device__ __forceinline__ void stage_w(const float* __restrict__ W, int h0,
                                        float (*wbuf)[132], int tid) {
#pragma unroll
    for (int r = 0; r < 2; ++r) {
        int q  = tid + r * 256;          // 0..511
        int g  = q >> 2;                 // 0..127
        int c4 = q & 3;                  // 0..3
        float4 v = *(const float4*)(W + g * HIDDEN + h0 + c4 * 4);
        wbuf[c4 * 4 + 0][g] = v.x;
        wbuf[c4 * 4 + 1][g] = v.y;
        wbuf[c4 * 4 + 2][g] = v.z;
        wbuf[c4 * 4 + 3][g] = v.w;
    }
}

__global__ __launch_bounds__(BLOCK, 2)
void sinr_main(const float* __restrict__ x,
               const float* __restrict__ Wftr,
               const float* __restrict__ bftr,
               const float* __restrict__ Wfwd,
               const float* __restrict__ Wout,
               const float* __restrict__ boutp,
               const float* __restrict__ cterm,
               float* __restrict__ out,
               float* __restrict__ out_x) {
    __shared__ float ylds[PTS_PER_BLOCK][56];    // [p][s*9 + (m+4)], 54 used
    __shared__ float zbuf[PTS_PER_BLOCK][132];   // [p][h], pad 132 breaks conflicts
    __shared__ float wlds[2][16][132];           // [buf][hh][g]
    __shared__ float coefs[54];

    const int tid = threadIdx.x;
    const int p0  = blockIdx.x * PTS_PER_BLOCK;  // first point of this block
    const int b   = p0 >> 15;                    // / 32768 — uniform per block

    // --- normalization coefficient table (double precision, once per block) --
    if (tid < 54) {
        int s  = tid / 9;
        int mm = tid % 9 - 4;
        int am = mm < 0 ? -mm : mm;
        int l  = am + s;
        double ratio = 1.0;                      // (l+am)!/(l-am)!
        for (int k = l - am + 1; k <= l + am; ++k) ratio *= (double)k;
        double norm = sqrt((2.0 * l + 1.0) / (4.0 * M_PI * ratio));
        double cf = (mm == 0) ? norm
                              : ((am & 1) ? -1.0 : 1.0) * sqrt(2.0) * norm;
        coefs[tid] = (float)cf;
    }

    // passthrough copy of x (output 1)
    if (tid < 2 * PTS_PER_BLOCK) {
        out_x[p0 * 2 + tid] = x[p0 * 2 + tid];
    }
    __syncthreads();

    // --- per-point spherical harmonics: Y[s][m] for s=0..5, m=-4..4 ----------
    if (tid < PTS_PER_BLOCK) {
        float th = x[(p0 + tid) * 2 + 0];
        float ph = x[(p0 + tid) * 2 + 1];
        float c  = cosf(ph);
        float somx2 = sqrtf(fmaxf(1.0f - c * c, 0.0f));
        // cos(k*th), sin(k*th), k=0..4 via angle addition
        float s1, c1;
        sincosf(th, &s1, &c1);
        float ctab[5], stab[5];
        ctab[0] = 1.0f; stab[0] = 0.0f;
        ctab[1] = c1;   stab[1] = s1;
#pragma unroll
        for (int k = 2; k <= 4; ++k) {
            ctab[k] = ctab[k - 1] * c1 - stab[k - 1] * s1;
            stab[k] = stab[k - 1] * c1 + ctab[k - 1] * s1;
        }
        // associated Legendre P_{am+s}^{am}(c) for am=0..4, s=0..5
        float P[5][6];
        float pmm = 1.0f;
#pragma unroll
        for (int am = 0; am <= 4; ++am) {
            if (am > 0) pmm *= -(2.0f * am - 1.0f) * somx2;
            float pm2 = pmm;                          // l = am
            float pm1 = c * (2.0f * am + 1.0f) * pmm; // l = am+1
            P[am][0] = pm2;
            P[am][1] = pm1;
#pragma unroll
            for (int s = 2; s < 6; ++s) {
                int l = am + s;
                float pl = ((2.0f * l - 1.0f) * c * pm1
                            - (float)(l + am - 1) * pm2) / (float)(l - am);
                P[am][s] = pl;
                pm2 = pm1;
                pm1 = pl;
            }
        }
#pragma unroll
        for (int s = 0; s < 6; ++s) {
#pragma unroll
            for (int mm = -4; mm <= 4; ++mm) {
                int am = mm < 0 ? -mm : mm;
                float trig = (mm > 0) ? ctab[am] : ((mm < 0) ? stab[am] : 1.0f);
                ylds[tid][s * 9 + mm + 4] = coefs[s * 9 + mm + 4] * P[am][s] * trig;
            }
        }
    }
    __syncthreads();

    // thread tile: tx -> 8 hidden outputs, ty -> 4 points
    const int tx = tid & 15;
    const int ty = tid >> 4;
    const int g0 = tx * 8;
    const int pb = ty * 4;

    // --- z init: z = ystack[0] @ Wftr[0]^T + bftr[0] --------------------------
    {
#pragma unroll
        for (int k = 0; k < 8; ++k) {
            int g = g0 + k;
            const float* wr = Wftr + g * NFREQ;     // s=0
            float w[9];
#pragma unroll
            for (int m2 = 0; m2 < 9; ++m2) w[m2] = wr[m2];
            float bb = bftr[g];
#pragma unroll
            for (int j = 0; j < 4; ++j) {
                float acc = bb;
#pragma unroll
                for (int m2 = 0; m2 < 9; ++m2)
                    acc = fmaf(ylds[pb + j][m2], w[m2], acc);
                zbuf[pb + j][g] = acc;
            }
        }
    }

    // --- 5 layers: z = (z @ Wfwd^T + cterm) * (ystack[s] @ Wftr[s]^T + bftr[s])
    for (int layer = 0; layer < DEPTH; ++layer) {
        const float* W = Wfwd + layer * HIDDEN * HIDDEN;
        float acc[4][8];
#pragma unroll
        for (int j = 0; j < 4; ++j)
#pragma unroll
            for (int k = 0; k < 8; ++k) acc[j][k] = 0.0f;

        stage_w(W, 0, wlds[0], tid);
        __syncthreads();   // also guards zbuf writes from previous layer

        for (int hc = 0; hc < 8; ++hc) {
            if (hc < 7) stage_w(W, (hc + 1) * 16, wlds[(hc + 1) & 1], tid);
            const int h0 = hc * 16;
            const float (*wb)[132] = wlds[hc & 1];
#pragma unroll
            for (int hh = 0; hh < 16; ++hh) {
                float4 wv0 = *(const float4*)(&wb[hh][g0]);
                float4 wv1 = *(const float4*)(&wb[hh][g0 + 4]);
                float zv[4];
#pragma unroll
                for (int j = 0; j < 4; ++j) zv[j] = zbuf[pb + j][h0 + hh];
#pragma unroll
                for (int j = 0; j < 4; ++j) {
                    acc[j][0] = fmaf(zv[j], wv0.x, acc[j][0]);
                    acc[j][1] = fmaf(zv[j], wv0.y, acc[j][1]);
                    acc[j][2] = fmaf(zv[j], wv0.z, acc[j][2]);
                    acc[j][3] = fmaf(zv[j], wv0.w, acc[j][3]);
                    acc[j][4] = fmaf(zv[j], wv1.x, acc[j][4]);
                    acc[j][5] = fmaf(zv[j], wv1.y, acc[j][5]);
                    acc[j][6] = fmaf(zv[j], wv1.z, acc[j][6]);
                    acc[j][7] = fmaf(zv[j], wv1.w, acc[j][7]);
                }
            }
            __syncthreads();
        }

        // epilogue: add code term, modulate by next filter, write back to zbuf
        const int sft = layer + 1;
        const float* ct = cterm + (layer * BATCH + b) * HIDDEN;
#pragma unroll
        for (int k = 0; k < 8; ++k) {
            int g = g0 + k;
            const float* wr = Wftr + (sft * HIDDEN + g) * NFREQ;
            float w[9];
#pragma unroll
            for (int m2 = 0; m2 < 9; ++m2) w[m2] = wr[m2];
            float bb   = bftr[sft * HIDDEN + g];
            float cadd = ct[g];
#pragma unroll
            for (int j = 0; j < 4; ++j) {
                float f = bb;
#pragma unroll
                for (int m2 = 0; m2 < 9; ++m2)
                    f = fmaf(ylds[pb + j][sft * 9 + m2], w[m2], f);
                zbuf[pb + j][g] = (acc[j][k] + cadd) * f;
            }
        }
        __syncthreads();
    }

    // --- final: out[p] = z . Wout + bout -------------------------------------
    if (tid < PTS_PER_BLOCK) {
        int p = tid;
        float accf = boutp[0];
        for (int h = 0; h < HIDDEN; h += 4) {
            float4 zz = *(const float4*)(&zbuf[p][h]);
            float4 ww = *(const float4*)(Wout + h);
            accf = fmaf(zz.x, ww.x, accf);
            accf = fmaf(zz.y, ww.y, accf);
            accf = fmaf(zz.z, ww.z, accf);
            accf = fmaf(zz.w, ww.w, accf);
        }
        out[p0 + p] = accf;
    }
}

// ---------------------------------------------------------------------------
extern "C" void kernel_launch(void* const* d_in, const int* in_sizes, int n_in,
                              void* d_out, int out_size, void* d_ws, size_t ws_size,
                              hipStream_t stream) {
    (void)in_sizes; (void)n_in; (void)out_size; (void)ws_size;
    const float* x     = (const float*)d_in[0];
    const float* a     = (const float*)d_in[1];
    const float* Wftr  = (const float*)d_in[2];
    const float* bftr  = (const float*)d_in[3];
    const float* Wfwd  = (const float*)d_in[4];
    const float* bfwd  = (const float*)d_in[5];
    const float* Wcode = (const float*)d_in[6];
    const float* bcode = (const float*)d_in[7];
    const float* Wout  = (const float*)d_in[8];
    const float* bout  = (const float*)d_in[9];

    float* out   = (float*)d_out;            // [B*N]
    float* out_x = out + NPTS;               // [B*N*2] passthrough
    float* cterm = (float*)d_ws;             // [DEPTH][BATCH][HIDDEN]

    sinr_cterm<<<DEPTH * BATCH, HIDDEN, 0, stream>>>(a, Wcode, bcode, bfwd, cterm);
    sinr_main<<<NPTS / PTS_PER_BLOCK, BLOCK, 0, stream>>>(
        x, Wftr, bftr, Wfwd, Wout, bout, cterm, out, out_x);
}

// Round 2
// 762.023 us; speedup vs baseline: 1.0838x; 1.0838x over previous
//
#include <hip/hip_runtime.h>
#include <math.h>

// Problem constants (match reference)
#define DEPTH   5
#define HIDDEN  128
#define CODE    400
#define NFREQ   9
#define BATCH   8
#define NPTS    262144

#define PTSB    64     // points per block
#define BLOCK   256
#define S_Z     68     // zT row stride (words): h-rows of 64 pts + pad
#define S_W     132    // wlds row stride
#define S_F     13     // staged filter row stride (13 breaks 8-way conflicts)

// ---------------------------------------------------------------------------
// Prep kernel: (a) cterm[i][b][h] = a[b]·Wcode[i][h] + bcode + bfwd
//              (b) wftr2 = Wftr × (sph-harm normalization coef, folded)
// ---------------------------------------------------------------------------
__global__ void sinr_prep(const float* __restrict__ a,
                          const float* __restrict__ Wcode,
                          const float* __restrict__ bcode,
                          const float* __restrict__ bfwd,
                          const float* __restrict__ Wftr,
                          float* __restrict__ cterm,
                          float* __restrict__ wftr2) {
    int blk = blockIdx.x, tid = threadIdx.x;
    if (blk < DEPTH * BATCH) {
        if (tid < HIDDEN) {
            int i = blk / BATCH, b = blk % BATCH, h = tid;
            const float* ar = a + b * CODE;
            const float* wr = Wcode + (i * HIDDEN + h) * CODE;
            float acc = bcode[i * HIDDEN + h] + bfwd[i * HIDDEN + h];
            for (int c = 0; c < CODE; c += 4) {
                float4 av = *(const float4*)(ar + c);
                float4 wv = *(const float4*)(wr + c);
                acc = fmaf(av.x, wv.x, acc);
                acc = fmaf(av.y, wv.y, acc);
                acc = fmaf(av.z, wv.z, acc);
                acc = fmaf(av.w, wv.w, acc);
            }
            cterm[(i * BATCH + b) * HIDDEN + h] = acc;
        }
    } else {
        int idx = (blk - DEPTH * BATCH) * BLOCK + tid;
        if (idx < (DEPTH + 1) * HIDDEN * NFREQ) {
            int s  = idx / (HIDDEN * NFREQ);
            int mm = idx % NFREQ - 4;
            int am = mm < 0 ? -mm : mm;
            int l  = am + s;
            double ratio = 1.0;                    // (l+am)!/(l-am)!
            for (int k = l - am + 1; k <= l + am; ++k) ratio *= (double)k;
            double norm = sqrt((2.0 * l + 1.0) / (4.0 * M_PI * ratio));
            double cf = (mm == 0) ? norm
                                  : ((am & 1) ? -1.0 : 1.0) * sqrt(2.0) * norm;
            wftr2[idx] = Wftr[idx] * (float)cf;
        }
    }
}

// ---------------------------------------------------------------------------
// Wfwd chunk staging: global [g][h] -> LDS transposed [hh][g], stride S_W.
// Writes land 2-way per bank (free).
// ---------------------------------------------------------------------------
__device__ __forceinline__ void stage_w(const float* __restrict__ W, int h0,
                                        float (*wbuf)[S_W], int tid) {
#pragma unroll
    for (int r = 0; r < 2; ++r) {
        int q  = tid + r * 256;          // 0..511
        int g  = q >> 2;                 // 0..127
        int c4 = q & 3;                  // 0..3
        float4 v = *(const float4*)(W + g * HIDDEN + h0 + c4 * 4);
        wbuf[c4 * 4 + 0][g] = v.x;
        wbuf[c4 * 4 + 1][g] = v.y;
        wbuf[c4 * 4 + 2][g] = v.z;
        wbuf[c4 * 4 + 3][g] = v.w;
    }
}

// ---------------------------------------------------------------------------
// Main fused pipeline. 256 threads, 64 points.
// zT[h][p] transposed in LDS. Thread tile: 4 points (ty) x 8 g-cols (tx,
// split halves g=tx*4.. and g=64+tx*4.. for conflict-free W reads).
// ---------------------------------------------------------------------------
__global__ __launch_bounds__(BLOCK, 2)
void sinr_main(const float* __restrict__ x,
               const float* __restrict__ wftr2,
               const float* __restrict__ bftr,
               const float* __restrict__ Wfwd,
               const float* __restrict__ Wout,
               const float* __restrict__ boutp,
               const float* __restrict__ cterm,
               float* __restrict__ out,
               float* __restrict__ out_x) {
    __shared__ float ylds[PTSB][54];        // [p][s*9+(m+4)] = P*trig (no coef)
    __shared__ float zT[HIDDEN][S_Z];       // transposed z: [h][p]
    __shared__ float wlds[2][16][S_W];      // Wfwd chunks [hh][g]

    // wlds[0] region doubles as per-layer filter/cterm/bftr stage (hc==7)
    float* const fl   = &wlds[0][0][0];
    float* const f_w  = fl;                         // [128][S_F]
    float* const f_ct = fl + HIDDEN * S_F;          // [128]
    float* const f_bf = fl + HIDDEN * S_F + HIDDEN; // [128]

    const int tid = threadIdx.x;
    const int p0  = blockIdx.x * PTSB;
    const int b   = p0 >> 15;
    const int tx  = tid & 15, ty = tid >> 4;
    const int pb  = ty * 4, ga = tx * 4;

    // stage layer-0 filter slice into f_w
    for (int e = tid; e < HIDDEN * NFREQ; e += BLOCK) {
        int g = e / 9, m = e % 9;
        f_w[g * S_F + m] = wftr2[e];
    }
    // passthrough copy of x (output 1)
    if (tid < 2 * PTSB) out_x[p0 * 2 + tid] = x[p0 * 2 + tid];

    // --- per-point spherical harmonics: P*trig for s=0..5, m=-4..4 ----------
    if (tid < PTSB) {
        float th = x[(p0 + tid) * 2 + 0];
        float ph = x[(p0 + tid) * 2 + 1];
        float c  = cosf(ph);
        float somx2 = sqrtf(fmaxf(1.0f - c * c, 0.0f));
        float s1, c1;
        sincosf(th, &s1, &c1);
        float ctab[5], stab[5];
        ctab[0] = 1.0f; stab[0] = 0.0f;
        ctab[1] = c1;   stab[1] = s1;
#pragma unroll
        for (int k = 2; k <= 4; ++k) {
            ctab[k] = ctab[k - 1] * c1 - stab[k - 1] * s1;
            stab[k] = stab[k - 1] * c1 + ctab[k - 1] * s1;
        }
        float P[5][6];
        float pmm = 1.0f;
#pragma unroll
        for (int am = 0; am <= 4; ++am) {
            if (am > 0) pmm *= -(2.0f * am - 1.0f) * somx2;
            float pm2 = pmm;
            float pm1 = c * (2.0f * am + 1.0f) * pmm;
            P[am][0] = pm2;
            P[am][1] = pm1;
#pragma unroll
            for (int s = 2; s < 6; ++s) {
                int l = am + s;
                float pl = ((2.0f * l - 1.0f) * c * pm1
                            - (float)(l + am - 1) * pm2) / (float)(l - am);
                P[am][s] = pl;
                pm2 = pm1;
                pm1 = pl;
            }
        }
#pragma unroll
        for (int s = 0; s < 6; ++s) {
#pragma unroll
            for (int mm = -4; mm <= 4; ++mm) {
                int am = mm < 0 ? -mm : mm;
                float trig = (mm > 0) ? ctab[am] : ((mm < 0) ? stab[am] : 1.0f);
                ylds[tid][s * 9 + mm + 4] = P[am][s] * trig;
            }
        }
    }
    __syncthreads();

    // --- z init: z0 = ystack0 @ Wftr'[0]^T + bftr[0], write transposed ------
    {
#pragma unroll
        for (int k = 0; k < 8; ++k) {
            int g = (k < 4) ? (ga + k) : (64 + ga + (k - 4));
            const float* wf = &f_w[g * S_F];
            float bb = bftr[g];
            float r[4];
#pragma unroll
            for (int j = 0; j < 4; ++j) {
                float acc = bb;
#pragma unroll
                for (int m = 0; m < 9; ++m)
                    acc = fmaf(ylds[pb + j][m], wf[m], acc);
                r[j] = acc;
            }
            *(float4*)&zT[g][pb] = make_float4(r[0], r[1], r[2], r[3]);
        }
    }

    // --- 5 layers ------------------------------------------------------------
    for (int layer = 0; layer < DEPTH; ++layer) {
        const float* W = Wfwd + layer * HIDDEN * HIDDEN;
        const int sft = layer + 1;
        float acc[4][8];
#pragma unroll
        for (int j = 0; j < 4; ++j)
#pragma unroll
            for (int k = 0; k < 8; ++k) acc[j][k] = 0.0f;

        __syncthreads();   // previous epilogue/init readers of f_w / zT done
        stage_w(W, 0, wlds[0], tid);
        __syncthreads();

        for (int hc = 0; hc < 8; ++hc) {
            if (hc < 7) {
                stage_w(W, (hc + 1) * 16, wlds[(hc + 1) & 1], tid);
            } else {
                // stage next filter slice + cterm + bftr into wlds[0] region
                for (int e = tid; e < HIDDEN * NFREQ; e += BLOCK) {
                    int g = e / 9, m = e % 9;
                    f_w[g * S_F + m] = wftr2[sft * HIDDEN * NFREQ + e];
                }
                if (tid < HIDDEN)
                    f_ct[tid] = cterm[(layer * BATCH + b) * HIDDEN + tid];
                else
                    f_bf[tid - HIDDEN] = bftr[sft * HIDDEN + (tid - HIDDEN)];
            }
            const float (*wb)[S_W] = wlds[hc & 1];
            const int h0 = hc * 16;
#pragma unroll
            for (int hh = 0; hh < 16; ++hh) {
                float4 zq  = *(const float4*)&zT[h0 + hh][pb];
                float4 wv0 = *(const float4*)&wb[hh][ga];
                float4 wv1 = *(const float4*)&wb[hh][64 + ga];
                float zv[4] = {zq.x, zq.y, zq.z, zq.w};
#pragma unroll
                for (int j = 0; j < 4; ++j) {
                    acc[j][0] = fmaf(zv[j], wv0.x, acc[j][0]);
                    acc[j][1] = fmaf(zv[j], wv0.y, acc[j][1]);
                    acc[j][2] = fmaf(zv[j], wv0.z, acc[j][2]);
                    acc[j][3] = fmaf(zv[j], wv0.w, acc[j][3]);
                    acc[j][4] = fmaf(zv[j], wv1.x, acc[j][4]);
                    acc[j][5] = fmaf(zv[j], wv1.y, acc[j][5]);
                    acc[j][6] = fmaf(zv[j], wv1.z, acc[j][6]);
                    acc[j][7] = fmaf(zv[j], wv1.w, acc[j][7]);
                }
            }
            __syncthreads();
        }

        // epilogue: (acc + cterm) * filter, write back transposed
#pragma unroll
        for (int k = 0; k < 8; ++k) {
            int g = (k < 4) ? (ga + k) : (64 + ga + (k - 4));
            const float* wf = &f_w[g * S_F];
            float bb   = f_bf[g];
            float cadd = f_ct[g];
            float r[4];
#pragma unroll
            for (int j = 0; j < 4; ++j) {
                float f = bb;
#pragma unroll
                for (int m = 0; m < 9; ++m)
                    f = fmaf(ylds[pb + j][sft * 9 + m], wf[m], f);
                r[j] = (acc[j][k] + cadd) * f;
            }
            *(float4*)&zT[g][pb] = make_float4(r[0], r[1], r[2], r[3]);
        }
    }
    __syncthreads();

    // --- final: out[p] = z . Wout + bout, 4-way split over h ----------------
    {
        int p = tid & 63, q = tid >> 6;
        float accf = 0.0f;
        for (int h = q * 32; h < q * 32 + 32; ++h)
            accf = fmaf(zT[h][p], Wout[h], accf);
        ylds[p][q] = accf;      // ylds dead after last epilogue: reuse as psum
    }
    __syncthreads();
    if (tid < PTSB) {
        out[p0 + tid] = boutp[0] + ylds[tid][0] + ylds[tid][1]
                                 + ylds[tid][2] + ylds[tid][3];
    }
}

// ---------------------------------------------------------------------------
extern "C" void kernel_launch(void* const* d_in, const int* in_sizes, int n_in,
                              void* d_out, int out_size, void* d_ws, size_t ws_size,
                              hipStream_t stream) {
    (void)in_sizes; (void)n_in; (void)out_size; (void)ws_size;
    const float* x     = (const float*)d_in[0];
    const float* a     = (const float*)d_in[1];
    const float* Wftr  = (const float*)d_in[2];
    const float* bftr  = (const float*)d_in[3];
    const float* Wfwd  = (const float*)d_in[4];
    const float* bfwd  = (const float*)d_in[5];
    const float* Wcode = (const float*)d_in[6];
    const float* bcode = (const float*)d_in[7];
    const float* Wout  = (const float*)d_in[8];
    const float* bout  = (const float*)d_in[9];

    float* out   = (float*)d_out;            // [B*N]
    float* out_x = out + NPTS;               // [B*N*2] passthrough
    float* cterm = (float*)d_ws;             // [DEPTH][BATCH][HIDDEN]
    float* wftr2 = cterm + DEPTH * BATCH * HIDDEN;  // [(DEPTH+1)][HIDDEN][NFREQ]

    int nprep = DEPTH * BATCH + ((DEPTH + 1) * HIDDEN * NFREQ + BLOCK - 1) / BLOCK;
    sinr_prep<<<nprep, BLOCK, 0, stream>>>(a, Wcode, bcode, bfwd, Wftr, cterm, wftr2);
    sinr_main<<<NPTS / PTSB, BLOCK, 0, stream>>>(
        x, wftr2, bftr, Wfwd, Wout, bout, cterm, out, out_x);
}

// Round 3
// 387.280 us; speedup vs baseline: 2.1325x; 1.9676x over previous
//
#include <hip/hip_runtime.h>
#include <math.h>

// Problem constants
#define DEPTH   5
#define HIDDEN  128
#define CODE    400
#define NFREQ   9
#define BATCH   8
#define NPTS    262144

#define PTSB    64
#define BLOCK   256
#define LW      72      // ylds row stride (floats): [6 shifts][12]

typedef __attribute__((ext_vector_type(8))) short sh8;
typedef __attribute__((ext_vector_type(4))) float f32x4;

__device__ __forceinline__ ushort f2bf(float f) {
    union { float f; uint u; } v; v.f = f;
    uint r = v.u + 0x7fffu + ((v.u >> 16) & 1u);
    return (ushort)(r >> 16);
}
__device__ __forceinline__ float bf2f(ushort h) {
    union { uint u; float f; } v; v.u = ((uint)h) << 16;
    return v.f;
}

// ---------------------------------------------------------------------------
// Prep: (a) cterm[i][b][h] = a·Wcode + bcode + bfwd
//       (b) wftr2 = Wftr × folded SH normalization coef
//       (c) Wfwd split into bf16 hi/lo images, pre-swizzled in LDS layout:
//           per (layer, kq): [g][ (kb ^ (g&3))*8 + j ]  (kb=(h>>3)&3, j=h&7)
// ---------------------------------------------------------------------------
__global__ void sinr_prep(const float* __restrict__ a,
                          const float* __restrict__ Wcode,
                          const float* __restrict__ bcode,
                          const float* __restrict__ bfwd,
                          const float* __restrict__ Wftr,
                          const float* __restrict__ Wfwd,
                          float* __restrict__ cterm,
                          float* __restrict__ wftr2,
                          ushort* __restrict__ whimg,
                          ushort* __restrict__ wlimg) {
    int blk = blockIdx.x, tid = threadIdx.x;
    if (blk < DEPTH * BATCH) {
        if (tid < HIDDEN) {
            int i = blk / BATCH, b = blk % BATCH, h = tid;
            const float* ar = a + b * CODE;
            const float* wr = Wcode + (i * HIDDEN + h) * CODE;
            float acc = bcode[i * HIDDEN + h] + bfwd[i * HIDDEN + h];
            for (int c = 0; c < CODE; c += 4) {
                float4 av = *(const float4*)(ar + c);
                float4 wv = *(const float4*)(wr + c);
                acc = fmaf(av.x, wv.x, acc);
                acc = fmaf(av.y, wv.y, acc);
                acc = fmaf(av.z, wv.z, acc);
                acc = fmaf(av.w, wv.w, acc);
            }
            cterm[(i * BATCH + b) * HIDDEN + h] = acc;
        }
    } else if (blk < DEPTH * BATCH + 27) {
        int idx = (blk - DEPTH * BATCH) * BLOCK + tid;
        if (idx < (DEPTH + 1) * HIDDEN * NFREQ) {
            int s  = idx / (HIDDEN * NFREQ);
            int mm = idx % NFREQ - 4;
            int am = mm < 0 ? -mm : mm;
            int l  = am + s;
            double ratio = 1.0;
            for (int k = l - am + 1; k <= l + am; ++k) ratio *= (double)k;
            double norm = sqrt((2.0 * l + 1.0) / (4.0 * M_PI * ratio));
            double cf = (mm == 0) ? norm
                                  : ((am & 1) ? -1.0 : 1.0) * sqrt(2.0) * norm;
            wftr2[idx] = Wftr[idx] * (float)cf;
        }
    } else {
        int idx = (blk - DEPTH * BATCH - 27) * BLOCK + tid;  // 0..81919
        if (idx < DEPTH * HIDDEN * HIDDEN) {
            int layer = idx >> 14;
            int r = idx & 16383;
            int g = r >> 7, h = r & 127;
            int kq = h >> 5, kb = (h >> 3) & 3, j = h & 7;
            float wv = Wfwd[idx];
            ushort hi = f2bf(wv);
            ushort lo = f2bf(wv - bf2f(hi));
            int dst = ((layer * 4 + kq) * HIDDEN + g) * 32 + ((kb ^ (g & 3)) * 8) + j;
            whimg[dst] = hi;
            wlimg[dst] = lo;
        }
    }
}

// ---------------------------------------------------------------------------
// Main fused pipeline with split-bf16 MFMA (16x16x32).
// Block: 256 threads (4 waves), 64 points.
// z images zh/zl: bf16 [p][128 h], chunk-swizzled: idx = p*128 + ((h>>3)^(p&15))*8 + (h&7)
// W quarter buffers wbh/wbl: bf16 [g][32 h], idx = g*32 + (kbl^(g&3))*8 + j
// Wave w: all 4 M-tiles (64 pts) × 2 N-tiles (g in [w*32, w*32+32)).
// ---------------------------------------------------------------------------
__global__ __launch_bounds__(BLOCK, 2)
void sinr_main(const float* __restrict__ x,
               const float* __restrict__ wftr2,
               const float* __restrict__ bftr,
               const ushort* __restrict__ whimg,
               const ushort* __restrict__ wlimg,
               const float* __restrict__ Wout,
               const float* __restrict__ boutp,
               const float* __restrict__ cterm,
               float* __restrict__ out,
               float* __restrict__ out_x) {
    __shared__ ushort zh[PTSB * HIDDEN], zl[PTSB * HIDDEN];      // 16 KB each
    __shared__ ushort wbh[HIDDEN * 32], wbl[HIDDEN * 32];        // 8 KB each
    __shared__ float  ylds[PTSB * LW];                           // 18 KB
    __shared__ float  fbuf[HIDDEN * 12];                         // 6 KB
    __shared__ float  ctb[HIDDEN], bfb[HIDDEN];

    const int tid  = threadIdx.x;
    const int lane = tid & 63;
    const int w    = tid >> 6;
    const int p0   = blockIdx.x * PTSB;
    const int b    = p0 >> 15;

    // ---- stage filter 0 + bftr[0]; x passthrough -----------------------------
    for (int e = tid; e < HIDDEN * NFREQ; e += BLOCK)
        fbuf[(e / 9) * 12 + (e % 9)] = wftr2[e];
    if (tid >= 128) bfb[tid - 128] = bftr[tid - 128];
    if (tid < 2 * PTSB) out_x[p0 * 2 + tid] = x[p0 * 2 + tid];

    // ---- per-point spherical harmonics (P*trig, coef folded into wftr2) -----
    if (tid < PTSB) {
        float th = x[(p0 + tid) * 2 + 0];
        float ph = x[(p0 + tid) * 2 + 1];
        float c  = cosf(ph);
        float somx2 = sqrtf(fmaxf(1.0f - c * c, 0.0f));
        float s1, c1;
        sincosf(th, &s1, &c1);
        float ctab[5], stab[5];
        ctab[0] = 1.0f; stab[0] = 0.0f;
        ctab[1] = c1;   stab[1] = s1;
#pragma unroll
        for (int k = 2; k <= 4; ++k) {
            ctab[k] = ctab[k - 1] * c1 - stab[k - 1] * s1;
            stab[k] = stab[k - 1] * c1 + ctab[k - 1] * s1;
        }
        float P[5][6];
        float pmm = 1.0f;
#pragma unroll
        for (int am = 0; am <= 4; ++am) {
            if (am > 0) pmm *= -(2.0f * am - 1.0f) * somx2;
            float pm2 = pmm;
            float pm1 = c * (2.0f * am + 1.0f) * pmm;
            P[am][0] = pm2;
            P[am][1] = pm1;
#pragma unroll
            for (int s = 2; s < 6; ++s) {
                int l = am + s;
                float pl = ((2.0f * l - 1.0f) * c * pm1
                            - (float)(l + am - 1) * pm2) / (float)(l - am);
                P[am][s] = pl;
                pm2 = pm1;
                pm1 = pl;
            }
        }
#pragma unroll
        for (int s = 0; s < 6; ++s) {
#pragma unroll
            for (int mm = -4; mm <= 4; ++mm) {
                int am = mm < 0 ? -mm : mm;
                float trig = (mm > 0) ? ctab[am] : ((mm < 0) ? stab[am] : 1.0f);
                ylds[tid * LW + s * 12 + mm + 4] = P[am][s] * trig;
            }
        }
    }
    __syncthreads();

    // ---- z init: z0 = y0 @ wftr'[0]^T + bftr[0], bf16 hi/lo, swizzled -------
    {
        int p = tid & 63, qd = tid >> 6;
        float yv[9];
#pragma unroll
        for (int m = 0; m < 9; ++m) yv[m] = ylds[p * LW + m];
#pragma unroll
        for (int cc = 0; cc < 4; ++cc) {
            int c = qd * 4 + cc;
            sh8 hs, ls;
#pragma unroll
            for (int j = 0; j < 8; ++j) {
                int h = c * 8 + j;
                float acc = bfb[h];
                const float* wf = &fbuf[h * 12];
#pragma unroll
                for (int m = 0; m < 9; ++m) acc = fmaf(yv[m], wf[m], acc);
                ushort hi = f2bf(acc);
                hs[j] = (short)hi;
                ls[j] = (short)f2bf(acc - bf2f(hi));
            }
            int idx = p * HIDDEN + ((c ^ (p & 15)) * 8);
            *(sh8*)&zh[idx] = hs;
            *(sh8*)&zl[idx] = ls;
        }
    }

    const int l15 = lane & 15, lq = lane >> 4;

    // ---- 5 layers ------------------------------------------------------------
    for (int layer = 0; layer < DEPTH; ++layer) {
        const int sft = layer + 1;
        f32x4 acc[4][2];
#pragma unroll
        for (int mt = 0; mt < 4; ++mt)
#pragma unroll
            for (int nt = 0; nt < 2; ++nt)
                acc[mt][nt] = (f32x4){0.f, 0.f, 0.f, 0.f};

        for (int kq = 0; kq < 4; ++kq) {
            __syncthreads();    // W buffer free; (kq==0) epilogue readers done
            {   // stage K-quarter of W hi/lo (verbatim, pre-swizzled)
                const ushort* gh = whimg + (layer * 4 + kq) * 4096;
                const ushort* gl = wlimg + (layer * 4 + kq) * 4096;
                int o = tid * 16;
                *(sh8*)&wbh[o]     = *(const sh8*)&gh[o];
                *(sh8*)&wbh[o + 8] = *(const sh8*)&gh[o + 8];
                *(sh8*)&wbl[o]     = *(const sh8*)&gl[o];
                *(sh8*)&wbl[o + 8] = *(const sh8*)&gl[o + 8];
            }
            if (kq == 0) {      // stage next filter + code/bias terms
                for (int e = tid; e < HIDDEN * NFREQ; e += BLOCK)
                    fbuf[(e / 9) * 12 + (e % 9)] = wftr2[sft * HIDDEN * NFREQ + e];
                if (tid < 128) ctb[tid] = cterm[(layer * BATCH + b) * HIDDEN + tid];
                else           bfb[tid - 128] = bftr[sft * HIDDEN + (tid - 128)];
            }
            __syncthreads();

            sh8 bh[2], bl[2], ah[4], al[4];
#pragma unroll
            for (int nt = 0; nt < 2; ++nt) {
                int g = w * 32 + nt * 16 + l15;
                int idx = g * 32 + ((lq ^ (g & 3)) * 8);
                bh[nt] = *(const sh8*)&wbh[idx];
                bl[nt] = *(const sh8*)&wbl[idx];
            }
#pragma unroll
            for (int mt = 0; mt < 4; ++mt) {
                int p = mt * 16 + l15;
                int kbg = kq * 4 + lq;
                int idx = p * HIDDEN + ((kbg ^ (p & 15)) * 8);
                ah[mt] = *(const sh8*)&zh[idx];
                al[mt] = *(const sh8*)&zl[idx];
            }
#pragma unroll
            for (int mt = 0; mt < 4; ++mt)
#pragma unroll
                for (int nt = 0; nt < 2; ++nt) {
                    acc[mt][nt] = __builtin_amdgcn_mfma_f32_16x16x32_bf16(
                        ah[mt], bh[nt], acc[mt][nt], 0, 0, 0);
                    acc[mt][nt] = __builtin_amdgcn_mfma_f32_16x16x32_bf16(
                        al[mt], bh[nt], acc[mt][nt], 0, 0, 0);
                    acc[mt][nt] = __builtin_amdgcn_mfma_f32_16x16x32_bf16(
                        ah[mt], bl[nt], acc[mt][nt], 0, 0, 0);
                }
        }
        __syncthreads();    // all z reads done before overwrite

        // ---- epilogue: z_next = (acc + ct) * (y·wf + bf), split-bf16 --------
        float wf0[9], wf1[9];
        int gc0 = w * 32 + l15, gc1 = gc0 + 16;
#pragma unroll
        for (int m = 0; m < 9; ++m) {
            wf0[m] = fbuf[gc0 * 12 + m];
            wf1[m] = fbuf[gc1 * 12 + m];
        }
        float ct0 = ctb[gc0], ct1 = ctb[gc1];
        float bf0 = bfb[gc0], bf1 = bfb[gc1];
#pragma unroll
        for (int mt = 0; mt < 4; ++mt) {
#pragma unroll
            for (int r = 0; r < 4; ++r) {
                int row = mt * 16 + lq * 4 + r;
                const float* yr = &ylds[row * LW + sft * 12];
                float4 ya = *(const float4*)yr;
                float4 yb = *(const float4*)(yr + 4);
                float  yc = yr[8];
#pragma unroll
                for (int nt = 0; nt < 2; ++nt) {
                    float f = nt ? bf1 : bf0;
                    const float* wf = nt ? wf1 : wf0;
                    f = fmaf(ya.x, wf[0], f); f = fmaf(ya.y, wf[1], f);
                    f = fmaf(ya.z, wf[2], f); f = fmaf(ya.w, wf[3], f);
                    f = fmaf(yb.x, wf[4], f); f = fmaf(yb.y, wf[5], f);
                    f = fmaf(yb.z, wf[6], f); f = fmaf(yb.w, wf[7], f);
                    f = fmaf(yc,   wf[8], f);
                    float val = (acc[mt][nt][r] + (nt ? ct1 : ct0)) * f;
                    float vo  = __shfl_xor(val, 1);
                    ushort hi_s = f2bf(val), hi_o = f2bf(vo);
                    ushort lo_s = f2bf(val - bf2f(hi_s));
                    ushort lo_o = f2bf(vo  - bf2f(hi_o));
                    int h  = (w * 32 + nt * 16 + l15) & ~1;
                    int idx = row * HIDDEN + (((h >> 3) ^ (row & 15)) * 8) + (h & 7);
                    uint pk = (lane & 1)
                        ? ((uint)lo_o | ((uint)lo_s << 16))
                        : ((uint)hi_s | ((uint)hi_o << 16));
                    ushort* base = (lane & 1) ? zl : zh;
                    *(uint*)&base[idx] = pk;
                }
            }
        }
    }
    __syncthreads();

    // ---- final: out[p] = (zh+zl) · Wout + bout ------------------------------
    {
        int p = tid & 63, qd = tid >> 6;
        float accf = 0.0f;
#pragma unroll
        for (int cc = 0; cc < 4; ++cc) {
            int c = qd * 4 + cc;
            int idx = p * HIDDEN + ((c ^ (p & 15)) * 8);
            sh8 vh = *(const sh8*)&zh[idx];
            sh8 vl = *(const sh8*)&zl[idx];
            float4 w0 = *(const float4*)&Wout[c * 8];
            float4 w1 = *(const float4*)&Wout[c * 8 + 4];
            accf = fmaf(bf2f((ushort)vh[0]) + bf2f((ushort)vl[0]), w0.x, accf);
            accf = fmaf(bf2f((ushort)vh[1]) + bf2f((ushort)vl[1]), w0.y, accf);
            accf = fmaf(bf2f((ushort)vh[2]) + bf2f((ushort)vl[2]), w0.z, accf);
            accf = fmaf(bf2f((ushort)vh[3]) + bf2f((ushort)vl[3]), w0.w, accf);
            accf = fmaf(bf2f((ushort)vh[4]) + bf2f((ushort)vl[4]), w1.x, accf);
            accf = fmaf(bf2f((ushort)vh[5]) + bf2f((ushort)vl[5]), w1.y, accf);
            accf = fmaf(bf2f((ushort)vh[6]) + bf2f((ushort)vl[6]), w1.z, accf);
            accf = fmaf(bf2f((ushort)vh[7]) + bf2f((ushort)vl[7]), w1.w, accf);
        }
        fbuf[p * 4 + qd] = accf;
    }
    __syncthreads();
    if (tid < PTSB) {
        out[p0 + tid] = boutp[0] + fbuf[tid * 4 + 0] + fbuf[tid * 4 + 1]
                                 + fbuf[tid * 4 + 2] + fbuf[tid * 4 + 3];
    }
}

// ---------------------------------------------------------------------------
extern "C" void kernel_launch(void* const* d_in, const int* in_sizes, int n_in,
                              void* d_out, int out_size, void* d_ws, size_t ws_size,
                              hipStream_t stream) {
    (void)in_sizes; (void)n_in; (void)out_size; (void)ws_size;
    const float* x     = (const float*)d_in[0];
    const float* a     = (const float*)d_in[1];
    const float* Wftr  = (const float*)d_in[2];
    const float* bftr  = (const float*)d_in[3];
    const float* Wfwd  = (const float*)d_in[4];
    const float* bfwd  = (const float*)d_in[5];
    const float* Wcode = (const float*)d_in[6];
    const float* bcode = (const float*)d_in[7];
    const float* Wout  = (const float*)d_in[8];
    const float* bout  = (const float*)d_in[9];

    float* out   = (float*)d_out;                       // [B*N]
    float* out_x = out + NPTS;                          // [B*N*2]
    float*  cterm = (float*)d_ws;                       // 5120 f
    float*  wftr2 = cterm + DEPTH * BATCH * HIDDEN;     // 6912 f
    ushort* whimg = (ushort*)(wftr2 + (DEPTH + 1) * HIDDEN * NFREQ);  // 81920 sh
    ushort* wlimg = whimg + DEPTH * HIDDEN * HIDDEN;    // 81920 sh

    int nprep = DEPTH * BATCH + 27 + (DEPTH * HIDDEN * HIDDEN + BLOCK - 1) / BLOCK;
    sinr_prep<<<nprep, BLOCK, 0, stream>>>(a, Wcode, bcode, bfwd, Wftr, Wfwd,
                                           cterm, wftr2, whimg, wlimg);
    sinr_main<<<NPTS / PTSB, BLOCK, 0, stream>>>(
        x, wftr2, bftr, whimg, wlimg, Wout, bout, cterm, out, out_x);
}

// Round 4
// 265.719 us; speedup vs baseline: 3.1081x; 1.4575x over previous
//
#include <hip/hip_runtime.h>
#include <math.h>

#define DEPTH   5
#define HIDDEN  128
#define CODE    400
#define NFREQ   9
#define BATCH   8
#define NPTS    262144

#define PTSB    64
#define BLOCK   256
#define LW      72      // ylds row stride (floats): [6 shifts][12]

typedef __attribute__((ext_vector_type(8))) short sh8;
typedef __attribute__((ext_vector_type(4))) float f32x4;

__device__ __forceinline__ ushort f2bf(float f) {
    union { float f; uint u; } v; v.f = f;
    uint r = v.u + 0x7fffu + ((v.u >> 16) & 1u);
    return (ushort)(r >> 16);
}

// ---------------------------------------------------------------------------
// Prep: (a) cterm[i][b][h] = a·Wcode + bcode + bfwd
//       (b) wfB: filter weights as bf16 hi/lo B-fragments (K=10: 9 y + bias)
//       (c) gwB: Wfwd as bf16 hi/lo B-fragments in per-lane load order
// Fragment order: [..][w][nt][img][lane][j]  (lane: n=w*32+nt*16+(lane&15),
//                  k = kq*32 + (lane>>4)*8 + j)
// ---------------------------------------------------------------------------
__global__ void sinr_prep(const float* __restrict__ a,
                          const float* __restrict__ Wcode,
                          const float* __restrict__ bcode,
                          const float* __restrict__ bfwd,
                          const float* __restrict__ Wftr,
                          const float* __restrict__ bftr,
                          const float* __restrict__ Wfwd,
                          float* __restrict__ cterm,
                          ushort* __restrict__ wfB,
                          ushort* __restrict__ gwB) {
    int blk = blockIdx.x, tid = threadIdx.x;
    if (blk < DEPTH * BATCH) {
        if (tid < HIDDEN) {
            int i = blk / BATCH, b = blk % BATCH, h = tid;
            const float* ar = a + b * CODE;
            const float* wr = Wcode + (i * HIDDEN + h) * CODE;
            float acc = bcode[i * HIDDEN + h] + bfwd[i * HIDDEN + h];
            for (int c = 0; c < CODE; c += 4) {
                float4 av = *(const float4*)(ar + c);
                float4 wv = *(const float4*)(wr + c);
                acc = fmaf(av.x, wv.x, acc);
                acc = fmaf(av.y, wv.y, acc);
                acc = fmaf(av.z, wv.z, acc);
                acc = fmaf(av.w, wv.w, acc);
            }
            cterm[(i * BATCH + b) * HIDDEN + h] = acc;
        }
    } else if (blk < DEPTH * BATCH + 192) {
        int e = (blk - DEPTH * BATCH) * BLOCK + tid;        // < 49152
        int j    = e & 7;
        int lane = (e >> 3) & 63;
        int img  = (e >> 9) & 1;
        int nt   = (e >> 10) & 1;
        int w    = (e >> 11) & 3;
        int sft  = e >> 13;                                  // 0..5
        int g = w * 32 + nt * 16 + (lane & 15);
        int k = (lane >> 4) * 8 + j;
        float val = 0.0f;
        if (k < 9) {
            int mm = k - 4;
            int am = mm < 0 ? -mm : mm;
            int l  = am + sft;
            double ratio = 1.0;
            for (int q = l - am + 1; q <= l + am; ++q) ratio *= (double)q;
            double norm = sqrt((2.0 * l + 1.0) / (4.0 * M_PI * ratio));
            double cf = (mm == 0) ? norm
                                  : ((am & 1) ? -1.0 : 1.0) * sqrt(2.0) * norm;
            val = Wftr[(sft * HIDDEN + g) * NFREQ + k] * (float)cf;
        } else if (k == 9) {
            val = bftr[sft * HIDDEN + g];
        }
        uint u = __float_as_uint(val);
        ushort hi = (ushort)(u >> 16);
        float rf = val - __uint_as_float(u & 0xFFFF0000u);
        wfB[e] = img ? f2bf(rf) : hi;
    } else {
        int e = (blk - DEPTH * BATCH - 192) * BLOCK + tid;  // < 655360
        if (e < DEPTH * 4 * 4 * 2 * 2 * 512) {
            int j    = e & 7;
            int lane = (e >> 3) & 63;
            int img  = (e >> 9) & 1;
            int nt   = (e >> 10) & 1;
            int w    = (e >> 11) & 3;
            int kq   = (e >> 13) & 3;
            int layer = e >> 15;
            int g = w * 32 + nt * 16 + (lane & 15);
            int h = kq * 32 + (lane >> 4) * 8 + j;
            float v = Wfwd[(layer * HIDDEN + g) * HIDDEN + h];
            uint u = __float_as_uint(v);
            ushort hi = (ushort)(u >> 16);
            float rf = v - __uint_as_float(u & 0xFFFF0000u);
            gwB[e] = img ? f2bf(rf) : hi;
        }
    }
}

// ---------------------------------------------------------------------------
// Main fused pipeline. 256 threads (4 waves), 64 points.
// z hi/lo bf16 images in LDS, chunk-swizzled; W and filter B-fragments come
// straight from global (L2). Filter matrix F computed by MFMA (bias folded).
// ---------------------------------------------------------------------------
__global__ __launch_bounds__(BLOCK, 3)
void sinr_main(const float* __restrict__ x,
               const ushort* __restrict__ wfB,
               const ushort* __restrict__ gwB,
               const float* __restrict__ cterm,
               const float* __restrict__ Wout,
               const float* __restrict__ boutp,
               float* __restrict__ out,
               float* __restrict__ out_x) {
    __shared__ ushort zh[PTSB * HIDDEN], zl[PTSB * HIDDEN];   // 16 KB each
    __shared__ float  ylds[PTSB * LW];                        // 18 KB

    const int tid  = threadIdx.x;
    const int lane = tid & 63;
    const int w    = tid >> 6;
    const int l15  = lane & 15, lq = lane >> 4;
    const int p0   = blockIdx.x * PTSB;
    const int b    = p0 >> 15;

    if (tid < 2 * PTSB) out_x[p0 * 2 + tid] = x[p0 * 2 + tid];

    // ---- per-point spherical harmonics: P*trig (coef folded into wfB) ------
    if (tid < PTSB) {
        float th = x[(p0 + tid) * 2 + 0];
        float ph = x[(p0 + tid) * 2 + 1];
        float c  = cosf(ph);
        float somx2 = sqrtf(fmaxf(1.0f - c * c, 0.0f));
        float s1, c1;
        sincosf(th, &s1, &c1);
        float ctab[5], stab[5];
        ctab[0] = 1.0f; stab[0] = 0.0f;
        ctab[1] = c1;   stab[1] = s1;
#pragma unroll
        for (int k = 2; k <= 4; ++k) {
            ctab[k] = ctab[k - 1] * c1 - stab[k - 1] * s1;
            stab[k] = stab[k - 1] * c1 + ctab[k - 1] * s1;
        }
        float P[5][6];
        float pmm = 1.0f;
#pragma unroll
        for (int am = 0; am <= 4; ++am) {
            if (am > 0) pmm *= -(2.0f * am - 1.0f) * somx2;
            float pm2 = pmm;
            float pm1 = c * (2.0f * am + 1.0f) * pmm;
            P[am][0] = pm2;
            P[am][1] = pm1;
#pragma unroll
            for (int s = 2; s < 6; ++s) {
                int l = am + s;
                float pl = ((2.0f * l - 1.0f) * c * pm1
                            - (float)(l + am - 1) * pm2) / (float)(l - am);
                P[am][s] = pl;
                pm2 = pm1;
                pm1 = pl;
            }
        }
#pragma unroll
        for (int s = 0; s < 6; ++s) {
#pragma unroll
            for (int mm = -4; mm <= 4; ++mm) {
                int am = mm < 0 ? -mm : mm;
                float trig = (mm > 0) ? ctab[am] : ((mm < 0) ? stab[am] : 1.0f);
                ylds[tid * LW + s * 12 + mm + 4] = P[am][s] * trig;
            }
        }
    }
    __syncthreads();

    // ---- helper lambdas -----------------------------------------------------
    auto build_yfrag = [&](int mt, int sft, sh8& yh, sh8& yl) {
        int row = mt * 16 + l15;
        const float* yr = &ylds[row * LW + sft * 12];
        float yv[8];
        if (lq == 0) {
            float4 a4 = *(const float4*)yr;
            float4 b4 = *(const float4*)(yr + 4);
            yv[0] = a4.x; yv[1] = a4.y; yv[2] = a4.z; yv[3] = a4.w;
            yv[4] = b4.x; yv[5] = b4.y; yv[6] = b4.z; yv[7] = b4.w;
        } else if (lq == 1) {
            yv[0] = yr[8]; yv[1] = 1.0f;
#pragma unroll
            for (int j = 2; j < 8; ++j) yv[j] = 0.0f;
        } else {
#pragma unroll
            for (int j = 0; j < 8; ++j) yv[j] = 0.0f;
        }
#pragma unroll
        for (int j = 0; j < 8; ++j) {
            uint u = __float_as_uint(yv[j]);
            yh[j] = (short)(u >> 16);
            float rf = yv[j] - __uint_as_float(u & 0xFFFF0000u);
            yl[j] = (short)(__float_as_uint(rf) >> 16);
        }
    };

    auto pack_store = [&](float val, int row, int gc) {
        uint u  = __float_as_uint(val);
        float rf = val - __uint_as_float(u & 0xFFFF0000u);
        uint ur = __float_as_uint(rf);
        uint uo  = __shfl_xor(u, 1);
        uint uro = __shfl_xor(ur, 1);
        int h = gc & ~1;
        int idx = row * HIDDEN + (((h >> 3) ^ (row & 15)) * 8) + (h & 7);
        if (lane & 1) *(uint*)&zl[idx] = (uro >> 16) | (ur & 0xFFFF0000u);
        else          *(uint*)&zh[idx] = (u   >> 16) | (uo & 0xFFFF0000u);
    };

    const int gc0 = w * 32 + l15, gc1 = gc0 + 16;

    // ---- z init via F-MFMA with sft=0 ---------------------------------------
    {
        const ushort* wfb = wfB + (0 * 4 + w) * 2048;
        sh8 wfh0 = *(const sh8*)&wfb[lane * 8];
        sh8 wfl0 = *(const sh8*)&wfb[512 + lane * 8];
        sh8 wfh1 = *(const sh8*)&wfb[1024 + lane * 8];
        sh8 wfl1 = *(const sh8*)&wfb[1536 + lane * 8];
        f32x4 f0[4][2];
#pragma unroll
        for (int mt = 0; mt < 4; ++mt) {
            f0[mt][0] = (f32x4){0.f, 0.f, 0.f, 0.f};
            f0[mt][1] = (f32x4){0.f, 0.f, 0.f, 0.f};
            sh8 yh, yl;
            build_yfrag(mt, 0, yh, yl);
            f0[mt][0] = __builtin_amdgcn_mfma_f32_16x16x32_bf16(yh, wfh0, f0[mt][0], 0, 0, 0);
            f0[mt][0] = __builtin_amdgcn_mfma_f32_16x16x32_bf16(yl, wfh0, f0[mt][0], 0, 0, 0);
            f0[mt][0] = __builtin_amdgcn_mfma_f32_16x16x32_bf16(yh, wfl0, f0[mt][0], 0, 0, 0);
            f0[mt][1] = __builtin_amdgcn_mfma_f32_16x16x32_bf16(yh, wfh1, f0[mt][1], 0, 0, 0);
            f0[mt][1] = __builtin_amdgcn_mfma_f32_16x16x32_bf16(yl, wfh1, f0[mt][1], 0, 0, 0);
            f0[mt][1] = __builtin_amdgcn_mfma_f32_16x16x32_bf16(yh, wfl1, f0[mt][1], 0, 0, 0);
        }
#pragma unroll
        for (int mt = 0; mt < 4; ++mt)
#pragma unroll
            for (int r = 0; r < 4; ++r) {
                int row = mt * 16 + lq * 4 + r;
                pack_store(f0[mt][0][r], row, gc0);
                pack_store(f0[mt][1][r], row, gc1);
            }
    }
    __syncthreads();

    // ---- 5 layers ------------------------------------------------------------
    for (int layer = 0; layer < DEPTH; ++layer) {
        const int sft = layer + 1;

        // F phase: facc = Y_sft @ Wf_sft (bias folded at k=9)
        f32x4 facc[4][2];
        {
            const ushort* wfb = wfB + (sft * 4 + w) * 2048;
            sh8 wfh0 = *(const sh8*)&wfb[lane * 8];
            sh8 wfl0 = *(const sh8*)&wfb[512 + lane * 8];
            sh8 wfh1 = *(const sh8*)&wfb[1024 + lane * 8];
            sh8 wfl1 = *(const sh8*)&wfb[1536 + lane * 8];
#pragma unroll
            for (int mt = 0; mt < 4; ++mt) {
                facc[mt][0] = (f32x4){0.f, 0.f, 0.f, 0.f};
                facc[mt][1] = (f32x4){0.f, 0.f, 0.f, 0.f};
                sh8 yh, yl;
                build_yfrag(mt, sft, yh, yl);
                facc[mt][0] = __builtin_amdgcn_mfma_f32_16x16x32_bf16(yh, wfh0, facc[mt][0], 0, 0, 0);
                facc[mt][0] = __builtin_amdgcn_mfma_f32_16x16x32_bf16(yl, wfh0, facc[mt][0], 0, 0, 0);
                facc[mt][0] = __builtin_amdgcn_mfma_f32_16x16x32_bf16(yh, wfl0, facc[mt][0], 0, 0, 0);
                facc[mt][1] = __builtin_amdgcn_mfma_f32_16x16x32_bf16(yh, wfh1, facc[mt][1], 0, 0, 0);
                facc[mt][1] = __builtin_amdgcn_mfma_f32_16x16x32_bf16(yl, wfh1, facc[mt][1], 0, 0, 0);
                facc[mt][1] = __builtin_amdgcn_mfma_f32_16x16x32_bf16(yh, wfl1, facc[mt][1], 0, 0, 0);
            }
        }

        // z phase: acc = z @ Wfwd (B-fragments direct from global/L2)
        f32x4 acc[4][2];
#pragma unroll
        for (int mt = 0; mt < 4; ++mt) {
            acc[mt][0] = (f32x4){0.f, 0.f, 0.f, 0.f};
            acc[mt][1] = (f32x4){0.f, 0.f, 0.f, 0.f};
        }
        for (int kq = 0; kq < 4; ++kq) {
            const ushort* gwb = gwB + ((layer * 4 + kq) * 4 + w) * 2048;
            sh8 bh0 = *(const sh8*)&gwb[lane * 8];
            sh8 bl0 = *(const sh8*)&gwb[512 + lane * 8];
            sh8 bh1 = *(const sh8*)&gwb[1024 + lane * 8];
            sh8 bl1 = *(const sh8*)&gwb[1536 + lane * 8];
            const int kbg = kq * 4 + lq;
#pragma unroll
            for (int mt = 0; mt < 4; ++mt) {
                int p = mt * 16 + l15;
                int idx = p * HIDDEN + ((kbg ^ (p & 15)) * 8);
                sh8 ah = *(const sh8*)&zh[idx];
                sh8 al = *(const sh8*)&zl[idx];
                acc[mt][0] = __builtin_amdgcn_mfma_f32_16x16x32_bf16(ah, bh0, acc[mt][0], 0, 0, 0);
                acc[mt][0] = __builtin_amdgcn_mfma_f32_16x16x32_bf16(al, bh0, acc[mt][0], 0, 0, 0);
                acc[mt][0] = __builtin_amdgcn_mfma_f32_16x16x32_bf16(ah, bl0, acc[mt][0], 0, 0, 0);
                acc[mt][1] = __builtin_amdgcn_mfma_f32_16x16x32_bf16(ah, bh1, acc[mt][1], 0, 0, 0);
                acc[mt][1] = __builtin_amdgcn_mfma_f32_16x16x32_bf16(al, bh1, acc[mt][1], 0, 0, 0);
                acc[mt][1] = __builtin_amdgcn_mfma_f32_16x16x32_bf16(ah, bl1, acc[mt][1], 0, 0, 0);
            }
        }

        float ct0 = cterm[(layer * BATCH + b) * HIDDEN + gc0];
        float ct1 = cterm[(layer * BATCH + b) * HIDDEN + gc1];
        __syncthreads();    // all z reads complete before overwrite

        // epilogue: z_next = (acc + ct) * facc
#pragma unroll
        for (int mt = 0; mt < 4; ++mt)
#pragma unroll
            for (int r = 0; r < 4; ++r) {
                int row = mt * 16 + lq * 4 + r;
                pack_store((acc[mt][0][r] + ct0) * facc[mt][0][r], row, gc0);
                pack_store((acc[mt][1][r] + ct1) * facc[mt][1][r], row, gc1);
            }
        __syncthreads();
    }

    // ---- final: out[p] = (zh+zl) · Wout + bout ------------------------------
    {
        int p = tid & 63, qd = tid >> 6;
        float accf = 0.0f;
#pragma unroll
        for (int cc = 0; cc < 4; ++cc) {
            int c = qd * 4 + cc;
            int idx = p * HIDDEN + ((c ^ (p & 15)) * 8);
            sh8 vh = *(const sh8*)&zh[idx];
            sh8 vl = *(const sh8*)&zl[idx];
            float4 w0 = *(const float4*)&Wout[c * 8];
            float4 w1 = *(const float4*)&Wout[c * 8 + 4];
#define BF(s) __uint_as_float(((uint)(ushort)(s)) << 16)
            accf = fmaf(BF(vh[0]) + BF(vl[0]), w0.x, accf);
            accf = fmaf(BF(vh[1]) + BF(vl[1]), w0.y, accf);
            accf = fmaf(BF(vh[2]) + BF(vl[2]), w0.z, accf);
            accf = fmaf(BF(vh[3]) + BF(vl[3]), w0.w, accf);
            accf = fmaf(BF(vh[4]) + BF(vl[4]), w1.x, accf);
            accf = fmaf(BF(vh[5]) + BF(vl[5]), w1.y, accf);
            accf = fmaf(BF(vh[6]) + BF(vl[6]), w1.z, accf);
            accf = fmaf(BF(vh[7]) + BF(vl[7]), w1.w, accf);
#undef BF
        }
        ylds[p * 4 + qd] = accf;
    }
    __syncthreads();
    if (tid < PTSB) {
        out[p0 + tid] = boutp[0] + ylds[tid * 4 + 0] + ylds[tid * 4 + 1]
                                 + ylds[tid * 4 + 2] + ylds[tid * 4 + 3];
    }
}

// ---------------------------------------------------------------------------
extern "C" void kernel_launch(void* const* d_in, const int* in_sizes, int n_in,
                              void* d_out, int out_size, void* d_ws, size_t ws_size,
                              hipStream_t stream) {
    (void)in_sizes; (void)n_in; (void)out_size; (void)ws_size;
    const float* x     = (const float*)d_in[0];
    const float* a     = (const float*)d_in[1];
    const float* Wftr  = (const float*)d_in[2];
    const float* bftr  = (const float*)d_in[3];
    const float* Wfwd  = (const float*)d_in[4];
    const float* bfwd  = (const float*)d_in[5];
    const float* Wcode = (const float*)d_in[6];
    const float* bcode = (const float*)d_in[7];
    const float* Wout  = (const float*)d_in[8];
    const float* bout  = (const float*)d_in[9];

    float* out   = (float*)d_out;                   // [B*N]
    float* out_x = out + NPTS;                      // [B*N*2]
    float*  cterm = (float*)d_ws;                   // 5120 floats
    ushort* wfB = (ushort*)(cterm + DEPTH * BATCH * HIDDEN);   // 49152 ushort
    ushort* gwB = wfB + 6 * 4 * 2 * 2 * 512;                   // 655360 ushort

    int nprep = DEPTH * BATCH + 192 + 2560;
    sinr_prep<<<nprep, BLOCK, 0, stream>>>(a, Wcode, bcode, bfwd, Wftr, bftr,
                                           Wfwd, cterm, wfB, gwB);
    sinr_main<<<NPTS / PTSB, BLOCK, 0, stream>>>(
        x, wfB, gwB, cterm, Wout, bout, out, out_x);
}

// Round 6
// 229.658 us; speedup vs baseline: 3.5961x; 1.1570x over previous
//
#include <hip/hip_runtime.h>
#include <math.h>

#define DEPTH   5
#define HIDDEN  128
#define CODE    400
#define NFREQ   9
#define BATCH   8
#define NPTS    262144
#define PTSB    64
#define BLOCK   256

typedef __attribute__((ext_vector_type(8))) short sh8;
typedef __attribute__((ext_vector_type(4))) float f32x4;
typedef __attribute__((ext_vector_type(4))) uint  u32x4;

__device__ __forceinline__ ushort f2bf(float f) {   // round-to-nearest-even
    union { float f; uint u; } v; v.f = f;
    uint r = v.u + 0x7fffu + ((v.u >> 16) & 1u);
    return (ushort)(r >> 16);
}

// Spherical-harmonic normalization coefficient (double precision)
__device__ __forceinline__ float sh_coef(int s, int yk) {
    int mm = yk - 4;
    int am = mm < 0 ? -mm : mm;
    int l  = am + s;
    double ratio = 1.0;
    for (int q = l - am + 1; q <= l + am; ++q) ratio *= (double)q;
    double norm = sqrt((2.0 * l + 1.0) / (4.0 * M_PI * ratio));
    double cf = (mm == 0) ? norm : ((am & 1) ? -1.0 : 1.0) * sqrt(2.0) * norm;
    return (float)cf;
}

// ---------------------------------------------------------------------------
// Prep.  cterm[i][b][h] = a·Wcode + bcode + bfwd.
// wfB: filter B-frags (K=32): slots (kq=0,j)=w[y_j]; (1,0)=(1,1)=w[y8];
//      (1,2)=bftr; (2,j)=w[y_j] (dup, pairs with yl); t=0 hi / t=1 rounded lo.
// gwB: Wfwd B-frags [layer][kq][ntg(8)][img][lane][j], hi / rounded lo.
// ---------------------------------------------------------------------------
__global__ void sinr_prep(const float* __restrict__ a,
                          const float* __restrict__ Wcode,
                          const float* __restrict__ bcode,
                          const float* __restrict__ bfwd,
                          const float* __restrict__ Wftr,
                          const float* __restrict__ bftr,
                          const float* __restrict__ Wfwd,
                          float* __restrict__ cterm,
                          ushort* __restrict__ wfB,
                          ushort* __restrict__ gwB) {
    int blk = blockIdx.x, tid = threadIdx.x;
    if (blk < DEPTH * BATCH) {
        if (tid < HIDDEN) {
            int i = blk / BATCH, b = blk % BATCH, h = tid;
            const float* ar = a + b * CODE;
            const float* wr = Wcode + (i * HIDDEN + h) * CODE;
            float acc = bcode[i * HIDDEN + h] + bfwd[i * HIDDEN + h];
            for (int c = 0; c < CODE; c += 4) {
                float4 av = *(const float4*)(ar + c);
                float4 wv = *(const float4*)(wr + c);
                acc = fmaf(av.x, wv.x, acc);
                acc = fmaf(av.y, wv.y, acc);
                acc = fmaf(av.z, wv.z, acc);
                acc = fmaf(av.w, wv.w, acc);
            }
            cterm[(i * BATCH + b) * HIDDEN + h] = acc;
        }
    } else if (blk < DEPTH * BATCH + 192) {
        int e = (blk - DEPTH * BATCH) * BLOCK + tid;     // < 49152
        int j    = e & 7;
        int lane = (e >> 3) & 63;
        int t    = (e >> 9) & 1;
        int nt   = (e >> 10) & 7;
        int s    = e >> 13;                               // 0..5
        int g  = nt * 16 + (lane & 15);
        int kq = lane >> 4;
        float v = 0.0f;
        if (kq == 0 || kq == 2) {
            v = sh_coef(s, j) * Wftr[(s * HIDDEN + g) * NFREQ + j];
        } else if (kq == 1) {
            if (j == 0 || j == 1)
                v = sh_coef(s, 8) * Wftr[(s * HIDDEN + g) * NFREQ + 8];
            else if (j == 2)
                v = bftr[s * HIDDEN + g];
        }
        uint u = __float_as_uint(v);
        float rf = v - __uint_as_float(u & 0xFFFF0000u);
        wfB[e] = t ? f2bf(rf) : (ushort)(u >> 16);
    } else {
        int e = (blk - DEPTH * BATCH - 192) * BLOCK + tid;  // < 163840
        if (e < DEPTH * 4 * 8 * 2 * 512) {
            int j     = e & 7;
            int lane  = (e >> 3) & 63;
            int img   = (e >> 9) & 1;
            int nt    = (e >> 10) & 7;
            int kq    = (e >> 13) & 3;
            int layer = e >> 15;
            int g = nt * 16 + (lane & 15);
            int h = kq * 32 + (lane >> 4) * 8 + j;
            float v = Wfwd[(layer * HIDDEN + g) * HIDDEN + h];
            uint u = __float_as_uint(v);
            float rf = v - __uint_as_float(u & 0xFFFF0000u);
            gwB[e] = img ? f2bf(rf) : (ushort)(u >> 16);
        }
    }
}

// ---------------------------------------------------------------------------
// Main. 4 waves; wave w owns cols w*32..+31 (2 N-tiles), all 64 rows (4 M-
// tiles) — R4's proven N-split with 2 barriers/layer. z packed one uint/elem
// (hi bf16 low16, lo bf16 high16), R4's swizzle phys_chunk = (h>>3)^(row&15).
// y A-fragments precomputed in LDS (ypk); F via 2 MFMAs (K-packed w/ dup).
// ---------------------------------------------------------------------------
__global__ __launch_bounds__(BLOCK, 3)
void sinr_main(const float* __restrict__ x,
               const ushort* __restrict__ wfB,
               const ushort* __restrict__ gwB,
               const float* __restrict__ cterm,
               const float* __restrict__ Wout,
               const float* __restrict__ boutp,
               float* __restrict__ out,
               float* __restrict__ out_x) {
    __shared__ __align__(16) uint   zz[PTSB * HIDDEN];       // 32 KB
    __shared__ __align__(16) ushort ypk[6 * 3 * PTSB * 8];   // 18 KB
    __shared__ __align__(16) ushort zrow[8];
    __shared__ float psum[BLOCK];

    const int tid  = threadIdx.x;
    const int lane = tid & 63;
    const int w    = tid >> 6;
    const int l15  = lane & 15, lq = lane >> 4;
    const int p0   = blockIdx.x * PTSB;
    const int b    = p0 >> 15;

    if (tid < 2 * PTSB) out_x[p0 * 2 + tid] = x[p0 * 2 + tid];
    if (tid >= 64 && tid < 72) zrow[tid - 64] = 0;

    // ---- harmonics + y A-fragments (hi / special / lo blocks per s) --------
    if (tid < PTSB) {
        float th = x[(p0 + tid) * 2 + 0];
        float ph = x[(p0 + tid) * 2 + 1];
        float c  = cosf(ph);
        float somx2 = sqrtf(fmaxf(1.0f - c * c, 0.0f));
        float s1, c1;
        sincosf(th, &s1, &c1);
        float ctab[5], stab[5];
        ctab[0] = 1.0f; stab[0] = 0.0f;
        ctab[1] = c1;   stab[1] = s1;
#pragma unroll
        for (int k = 2; k <= 4; ++k) {
            ctab[k] = ctab[k - 1] * c1 - stab[k - 1] * s1;
            stab[k] = stab[k - 1] * c1 + ctab[k - 1] * s1;
        }
        float P[5][6];
        float pmm = 1.0f;
#pragma unroll
        for (int am = 0; am <= 4; ++am) {
            if (am > 0) pmm *= -(2.0f * am - 1.0f) * somx2;
            float pm2 = pmm;
            float pm1 = c * (2.0f * am + 1.0f) * pmm;
            P[am][0] = pm2;
            P[am][1] = pm1;
#pragma unroll
            for (int s = 2; s < 6; ++s) {
                int l = am + s;
                float pl = ((2.0f * l - 1.0f) * c * pm1
                            - (float)(l + am - 1) * pm2) / (float)(l - am);
                P[am][s] = pl;
                pm2 = pm1;
                pm1 = pl;
            }
        }
#pragma unroll
        for (int s = 0; s < 6; ++s) {
            ushort yh[9], yl[9];
#pragma unroll
            for (int mm = -4; mm <= 4; ++mm) {
                int am = mm < 0 ? -mm : mm;
                float trig = (mm > 0) ? ctab[am] : ((mm < 0) ? stab[am] : 1.0f);
                float yv = P[am][s] * trig;
                uint u = __float_as_uint(yv);
                yh[mm + 4] = (ushort)(u >> 16);
                float rf = yv - __uint_as_float(u & 0xFFFF0000u);
                yl[mm + 4] = (ushort)(__float_as_uint(rf) >> 16);
            }
            sh8 k0, k1, k2;
#pragma unroll
            for (int j = 0; j < 8; ++j) { k0[j] = (short)yh[j]; k2[j] = (short)yl[j]; }
            k1[0] = (short)yh[8]; k1[1] = (short)yl[8]; k1[2] = (short)0x3F80;
            k1[3] = 0; k1[4] = 0; k1[5] = 0; k1[6] = 0; k1[7] = 0;
            int off = ((s * 3) * PTSB + tid) * 8;
            *(sh8*)&ypk[off]                = k0;
            *(sh8*)&ypk[off + PTSB * 8]     = k1;
            *(sh8*)&ypk[off + 2 * PTSB * 8] = k2;
        }
    }
    __syncthreads();

    auto packw = [](float val) -> uint {
        uint u = __float_as_uint(val);
        float rf = val - __uint_as_float(u & 0xFFFF0000u);
        return (u >> 16) | (__float_as_uint(rf) & 0xFFFF0000u);
    };
    // write: row = mt*16+lq*4+r, h = (w*2+nt)*16+l15
    auto zidx_w = [&](int mt, int nt, int r) -> int {
        int row = mt * 16 + lq * 4 + r;
        int hc  = (w * 2 + nt) * 2 + (l15 >> 3);
        return row * HIDDEN + ((hc ^ (row & 15)) << 3) + (l15 & 7);
    };
    // F phase for shift s -> facc[4][2]
    auto fphase = [&](int s, f32x4 (*facc)[2]) {
        sh8 wb1[2], wb2[2];
#pragma unroll
        for (int nt = 0; nt < 2; ++nt) {
            const ushort* wp = wfB + s * 8192 + (w * 2 + nt) * 1024 + lane * 8;
            wb1[nt] = *(const sh8*)wp;
            wb2[nt] = *(const sh8*)(wp + 512);
        }
#pragma unroll
        for (int mt = 0; mt < 4; ++mt) {
            const ushort* ya = (lq < 3)
                ? &ypk[(((s * 3 + lq) * PTSB) + mt * 16 + l15) * 8]
                : &zrow[0];
            sh8 yf = *(const sh8*)ya;
#pragma unroll
            for (int nt = 0; nt < 2; ++nt) {
                f32x4 t = (f32x4){0.f, 0.f, 0.f, 0.f};
                t = __builtin_amdgcn_mfma_f32_16x16x32_bf16(yf, wb1[nt], t, 0, 0, 0);
                t = __builtin_amdgcn_mfma_f32_16x16x32_bf16(yf, wb2[nt], t, 0, 0, 0);
                facc[mt][nt] = t;
            }
        }
    };

    // ---- z init: z0 = F(sft=0) ---------------------------------------------
    {
        f32x4 f0[4][2];
        fphase(0, f0);
#pragma unroll
        for (int mt = 0; mt < 4; ++mt)
#pragma unroll
            for (int nt = 0; nt < 2; ++nt)
#pragma unroll
                for (int r = 0; r < 4; ++r)
                    zz[zidx_w(mt, nt, r)] = packw(f0[mt][nt][r]);
    }
    __syncthreads();

    // ---- 5 layers (2 barriers/layer) ---------------------------------------
    for (int layer = 0; layer < DEPTH; ++layer) {
        f32x4 facc[4][2];
        fphase(layer + 1, facc);

        float ctv[2];
#pragma unroll
        for (int nt = 0; nt < 2; ++nt)
            ctv[nt] = cterm[(layer * BATCH + b) * HIDDEN + (w * 2 + nt) * 16 + l15];

        f32x4 acc[4][2];
#pragma unroll
        for (int mt = 0; mt < 4; ++mt)
#pragma unroll
            for (int nt = 0; nt < 2; ++nt)
                acc[mt][nt] = (f32x4){0.f, 0.f, 0.f, 0.f};

#pragma unroll
        for (int kq = 0; kq < 4; ++kq) {
            const ushort* gp = gwB + (layer * 4 + kq) * 8192 + lane * 8;
            sh8 bh[2], bl[2];
#pragma unroll
            for (int nt = 0; nt < 2; ++nt) {
                bh[nt] = *(const sh8*)(gp + (w * 2 + nt) * 1024);
                bl[nt] = *(const sh8*)(gp + (w * 2 + nt) * 1024 + 512);
            }
#pragma unroll
            for (int mt = 0; mt < 4; ++mt) {
                int row = mt * 16 + l15;
                int abase = row * HIDDEN + (((kq * 4 + lq) ^ l15) << 3);
                u32x4 a0 = *(const u32x4*)&zz[abase];
                u32x4 a1 = *(const u32x4*)&zz[abase + 4];
                uint uu[8] = {a0.x, a0.y, a0.z, a0.w, a1.x, a1.y, a1.z, a1.w};
                sh8 ah, al;
#pragma unroll
                for (int j = 0; j < 8; ++j) {
                    ah[j] = (short)(uu[j] & 0xFFFFu);
                    al[j] = (short)(uu[j] >> 16);
                }
#pragma unroll
                for (int nt = 0; nt < 2; ++nt) {
                    acc[mt][nt] = __builtin_amdgcn_mfma_f32_16x16x32_bf16(ah, bh[nt], acc[mt][nt], 0, 0, 0);
                    acc[mt][nt] = __builtin_amdgcn_mfma_f32_16x16x32_bf16(al, bh[nt], acc[mt][nt], 0, 0, 0);
                    acc[mt][nt] = __builtin_amdgcn_mfma_f32_16x16x32_bf16(ah, bl[nt], acc[mt][nt], 0, 0, 0);
                }
            }
        }
        __syncthreads();   // all z reads complete before overwrite

        // epilogue: z_next = (acc + ct) * F
#pragma unroll
        for (int mt = 0; mt < 4; ++mt)
#pragma unroll
            for (int nt = 0; nt < 2; ++nt)
#pragma unroll
                for (int r = 0; r < 4; ++r)
                    zz[zidx_w(mt, nt, r)] =
                        packw((acc[mt][nt][r] + ctv[nt]) * facc[mt][nt][r]);
        __syncthreads();   // all writes visible before next layer's reads
    }

    // ---- final: out[p] = (zh+zl) · Wout + bout ------------------------------
    {
        int p = tid & 63, qd = tid >> 6;
        float accf = 0.0f;
#pragma unroll
        for (int cc = 0; cc < 4; ++cc) {
            int hc = qd * 4 + cc;
            int base = p * HIDDEN + ((hc ^ (p & 15)) << 3);
            u32x4 a0 = *(const u32x4*)&zz[base];
            u32x4 a1 = *(const u32x4*)&zz[base + 4];
            uint uu[8] = {a0.x, a0.y, a0.z, a0.w, a1.x, a1.y, a1.z, a1.w};
            const float* wp = Wout + hc * 8;
#pragma unroll
            for (int j = 0; j < 8; ++j) {
                float hi = __uint_as_float(uu[j] << 16);
                float lo = __uint_as_float(uu[j] & 0xFFFF0000u);
                accf = fmaf(hi + lo, wp[j], accf);
            }
        }
        psum[qd * 64 + p] = accf;
    }
    __syncthreads();
    if (tid < PTSB) {
        out[p0 + tid] = boutp[0] + psum[tid] + psum[64 + tid]
                                 + psum[128 + tid] + psum[192 + tid];
    }
}

// ---------------------------------------------------------------------------
extern "C" void kernel_launch(void* const* d_in, const int* in_sizes, int n_in,
                              void* d_out, int out_size, void* d_ws, size_t ws_size,
                              hipStream_t stream) {
    (void)in_sizes; (void)n_in; (void)out_size; (void)ws_size;
    const float* x     = (const float*)d_in[0];
    const float* a     = (const float*)d_in[1];
    const float* Wftr  = (const float*)d_in[2];
    const float* bftr  = (const float*)d_in[3];
    const float* Wfwd  = (const float*)d_in[4];
    const float* bfwd  = (const float*)d_in[5];
    const float* Wcode = (const float*)d_in[6];
    const float* bcode = (const float*)d_in[7];
    const float* Wout  = (const float*)d_in[8];
    const float* bout  = (const float*)d_in[9];

    float* out   = (float*)d_out;                    // [B*N]
    float* out_x = out + NPTS;                       // [B*N*2]
    float*  cterm = (float*)d_ws;                    // 5120 floats
    ushort* wfB = (ushort*)(cterm + DEPTH * BATCH * HIDDEN);  // 49152 ushorts
    ushort* gwB = wfB + 49152;                                // 163840 ushorts

    int nprep = DEPTH * BATCH + 192 + 640;
    sinr_prep<<<nprep, BLOCK, 0, stream>>>(a, Wcode, bcode, bfwd, Wftr, bftr,
                                           Wfwd, cterm, wfB, gwB);
    sinr_main<<<NPTS / PTSB, BLOCK, 0, stream>>>(
        x, wfB, gwB, cterm, Wout, bout, out, out_x);
}